// Round 1
// baseline (417.449 us; speedup 1.0000x reference)
//
#include <hip/hip_runtime.h>

#define T_STEPS 100
#define CHUNKS 25   // 100 floats = 25 float4

// One thread per (b,n) element. Element's time series is contiguous (400 B,
// 16B-aligned since 400 = 25*16). Preload all 25 float4 chunks (max MLP),
// run the recurrence from registers, stream out 25 float4 stores.
//
// NUMERICS: spikes are 0/1; one ulp of drift in `mem` near THRESH flips a
// spike => absmax 1.0. We must be bit-identical to the numpy reference:
//   - fp contract OFF (no fma fusion; numpy rounds every op)
//   - exact op order:  mem = ((mem*TAU) + x) - w
//                      w   = (BETA*w) + (1-BETA)*((A*mem) + (B*spike))
//                      mem = mem - (spike*THRESH)
//   - constants as f32 roundings of the Python doubles:
//     TAU=0.5 exact, THRESH=0.5 exact, A=B=0.5 exact,
//     BETA -> 0.9f, (1.0-BETA)=0.09999999999999998 -> nearest f32 = 0.1f
//   - *0.5f is exact (exponent shift), so those multiplies never round.
__global__ __launch_bounds__(256) void lif_kernel(const float* __restrict__ x,
                                                  float* __restrict__ out,
                                                  int n_elem) {
#pragma clang fp contract(off)
    int e = blockIdx.x * blockDim.x + threadIdx.x;
    if (e >= n_elem) return;

    const float4* __restrict__ xp = (const float4*)(x + (size_t)e * T_STEPS);
    float4* __restrict__ op = (float4*)(out + (size_t)e * T_STEPS);

    // Preload entire 400B row into registers (25 outstanding 16B loads).
    float4 xs[CHUNKS];
#pragma unroll
    for (int c = 0; c < CHUNKS; ++c) xs[c] = xp[c];

    float mem = 0.0f;
    float w = 0.0f;

#pragma unroll
    for (int c = 0; c < CHUNKS; ++c) {
        float xv[4] = {xs[c].x, xs[c].y, xs[c].z, xs[c].w};
        float sv[4];
#pragma unroll
        for (int j = 0; j < 4; ++j) {
            mem = (mem * 0.5f + xv[j]) - w;                    // ((mem*TAU)+x)-w
            float spike = (mem - 0.5f) > 0.0f ? 1.0f : 0.0f;   // ZIF forward
            w = 0.9f * w + 0.1f * (0.5f * mem + 0.5f * spike); // (B*w)+(1-B)*((A*m)+(B*s))
            mem = mem - spike * 0.5f;                          // soft reset
            sv[j] = spike;
        }
        float4 s;
        s.x = sv[0]; s.y = sv[1]; s.z = sv[2]; s.w = sv[3];
        op[c] = s;
    }
}

extern "C" void kernel_launch(void* const* d_in, const int* in_sizes, int n_in,
                              void* d_out, int out_size, void* d_ws, size_t ws_size,
                              hipStream_t stream) {
    const float* x = (const float*)d_in[0];
    float* out = (float*)d_out;
    int n_elem = in_sizes[0] / T_STEPS;  // 64*8192 = 524288

    const int block = 256;
    const int grid = (n_elem + block - 1) / block;  // 2048 blocks
    lif_kernel<<<grid, block, 0, stream>>>(x, out, n_elem);
}

// Round 2
// 350.806 us; speedup vs baseline: 1.1900x; 1.1900x over previous
//
#include <hip/hip_runtime.h>

#define T_STEPS 100
#define CHUNKS  25    // 100 floats = 25 float4 per element
#define ELEMS   128   // elements per block
#define TPB     128   // threads per block (== ELEMS)
#define ROW4    32    // float4 slots per LDS row (power of 2 for XOR swizzle)
// LDS: 128 rows * 32 float4 * 16B = 65536 B exactly -> 2 blocks/CU (128/160 KB)

// XOR swizzle: row e, chunk c -> slot. c in [0,25), e&7 < 8 => c^(e&7) < 32.
//  - compute phase (fixed c, lanes = e): group (slot%8) = (c^(e&7))%8 takes all
//    8 values over e&7 -> same distribution as linear = conflict-free b128.
//  - staging phase (consecutive linear4 -> runs of same e, consecutive c):
//    each 8 consecutive c permute the 8 bank-groups -> conflict-free b128.
__device__ __forceinline__ int slot(int e, int c) {
    return e * ROW4 + (c ^ (e & 7));
}

// NUMERICS: bit-identical to numpy reference (verified R1, absmax 0):
//   fp contract OFF; op order ((mem*TAU)+x)-w ; (BETA*w)+(1-BETA)*((A*m)+(B*s));
//   mem - spike*THRESH ; BETA->0.9f, (1-BETA)->0.1f ; *0.5f exact.
__global__ __launch_bounds__(TPB) void lif_kernel(const float* __restrict__ x,
                                                  float* __restrict__ out) {
#pragma clang fp contract(off)
    __shared__ float4 tile[ELEMS * ROW4];

    const int tid = threadIdx.x;
    const size_t tile4 = (size_t)blockIdx.x * (ELEMS * CHUNKS);
    const float4* __restrict__ xb = (const float4*)x + tile4;
    float4* __restrict__ ob = (float4*)out + tile4;

    // ---- stage in: coalesced float4 global loads -> swizzled LDS rows ----
    // linear4 = k*TPB + tid ; e = linear4/25, c = linear4%25.
    // advance per k: linear4 += 128 = 5*25+3 -> e += 5, c += 3, carry.
    {
        int e = tid / 25;
        int c = tid - e * 25;
#pragma unroll
        for (int k = 0; k < CHUNKS; ++k) {
            float4 v = xb[k * TPB + tid];
            tile[slot(e, c)] = v;
            c += 3; e += 5;
            if (c >= CHUNKS) { c -= CHUNKS; e += 1; }
        }
    }
    __syncthreads();

    // ---- compute: thread = element, recurrence over its own LDS row ------
    // In-place: overwrite x chunk with spike chunk (own row only -> no race).
    {
        float mem = 0.0f;
        float w = 0.0f;
#pragma unroll
        for (int c = 0; c < CHUNKS; ++c) {
            float4 xv4 = tile[slot(tid, c)];
            float xv[4] = {xv4.x, xv4.y, xv4.z, xv4.w};
            float sv[4];
#pragma unroll
            for (int j = 0; j < 4; ++j) {
                mem = (mem * 0.5f + xv[j]) - w;                    // ((mem*TAU)+x)-w
                float spike = (mem - 0.5f) > 0.0f ? 1.0f : 0.0f;   // ZIF forward
                w = 0.9f * w + 0.1f * (0.5f * mem + 0.5f * spike); // numpy order
                mem = mem - spike * 0.5f;                          // soft reset
                sv[j] = spike;
            }
            float4 s4;
            s4.x = sv[0]; s4.y = sv[1]; s4.z = sv[2]; s4.w = sv[3];
            tile[slot(tid, c)] = s4;
        }
    }
    __syncthreads();

    // ---- stage out: swizzled LDS rows -> coalesced float4 global stores ---
    {
        int e = tid / 25;
        int c = tid - e * 25;
#pragma unroll
        for (int k = 0; k < CHUNKS; ++k) {
            float4 s = tile[slot(e, c)];
            ob[k * TPB + tid] = s;
            c += 3; e += 5;
            if (c >= CHUNKS) { c -= CHUNKS; e += 1; }
        }
    }
}

extern "C" void kernel_launch(void* const* d_in, const int* in_sizes, int n_in,
                              void* d_out, int out_size, void* d_ws, size_t ws_size,
                              hipStream_t stream) {
    const float* x = (const float*)d_in[0];
    float* out = (float*)d_out;
    int n_elem = in_sizes[0] / T_STEPS;       // 64*8192 = 524288
    int grid = n_elem / ELEMS;                // 4096 blocks, exact

    lif_kernel<<<grid, TPB, 0, stream>>>(x, out);
}

// Round 3
// 344.360 us; speedup vs baseline: 1.2122x; 1.0187x over previous
//
#include <hip/hip_runtime.h>

#define T_STEPS 100
#define CHUNKS  25    // 100 floats = 25 float4 per element
#define TPB     64    // one wave per block -> no real barriers
#define ELEMS   64    // elements per block (== TPB)
// LDS: 64 elems * 25 float4 * 16B = 25600 B -> 6 blocks/CU (153.6/160 KB)

typedef const __attribute__((address_space(1))) unsigned int g_u32;
typedef __attribute__((address_space(3))) unsigned int l_u32;

// Linear LDS layout: lds float4 slot i == global float4 index (tile-local) i.
//  - stage-in:  global_load_lds, lane-consecutive dest (base + lane*16) == linear
//  - compute:   lane e reads slot e*25+c (stride 400B): banks (4e+4c+d)%32 ->
//               uniform 8 dword-accesses/bank = minimum for 64 lanes x 16B
//  - stage-out: slot k*64+lane, stride-1 b128, conflict-free; stores coalesced
//
// NUMERICS: bit-identical to numpy reference (verified R1/R2, absmax 0):
//   fp contract OFF; op order ((mem*TAU)+x)-w ; (BETA*w)+(1-BETA)*((A*m)+(B*s));
//   mem - spike*THRESH ; BETA->0.9f, (1-BETA)->0.1f ; *0.5f exact (exp shift).
__global__ __launch_bounds__(TPB) void lif_kernel(const float* __restrict__ x,
                                                  float* __restrict__ out) {
#pragma clang fp contract(off)
    __shared__ float4 tile[ELEMS * CHUNKS];

    const int lane = threadIdx.x;
    const size_t tile4 = (size_t)blockIdx.x * (ELEMS * CHUNKS);
    const float4* __restrict__ xb = (const float4*)x + tile4;
    float4* __restrict__ ob = (float4*)out + tile4;

    // ---- stage in: async global->LDS DMA, 25 x 1KB per wave ----
#pragma unroll
    for (int k = 0; k < CHUNKS; ++k) {
        __builtin_amdgcn_global_load_lds(
            (g_u32*)(xb + k * TPB + lane),      // per-lane global src
            (l_u32*)&tile[k * TPB],             // wave-uniform LDS base
            16, 0, 0);                          // 16B/lane
    }
    __syncthreads();  // 1-wave block: compiles to the vmcnt/lgkm drain only

    // ---- compute: thread = element, recurrence over its own LDS row ------
    // In-place: overwrite x chunk with spike chunk (own slot, in-order DS).
    {
        float mem = 0.0f;
        float w = 0.0f;
#pragma unroll
        for (int c = 0; c < CHUNKS; ++c) {
            float4 xv4 = tile[lane * CHUNKS + c];
            float xv[4] = {xv4.x, xv4.y, xv4.z, xv4.w};
            float sv[4];
#pragma unroll
            for (int j = 0; j < 4; ++j) {
                mem = (mem * 0.5f + xv[j]) - w;                    // ((mem*TAU)+x)-w
                float spike = (mem - 0.5f) > 0.0f ? 1.0f : 0.0f;   // ZIF forward
                w = 0.9f * w + 0.1f * (0.5f * mem + 0.5f * spike); // numpy order
                mem = mem - spike * 0.5f;                          // soft reset
                sv[j] = spike;
            }
            float4 s4;
            s4.x = sv[0]; s4.y = sv[1]; s4.z = sv[2]; s4.w = sv[3];
            tile[lane * CHUNKS + c] = s4;
        }
    }
    __syncthreads();  // drain last ds_write before cross-lane stage-out reads

    // ---- stage out: stride-1 LDS reads -> coalesced float4 stores --------
#pragma unroll
    for (int k = 0; k < CHUNKS; ++k) {
        float4 s = tile[k * TPB + lane];
        ob[k * TPB + lane] = s;
    }
}

extern "C" void kernel_launch(void* const* d_in, const int* in_sizes, int n_in,
                              void* d_out, int out_size, void* d_ws, size_t ws_size,
                              hipStream_t stream) {
    const float* x = (const float*)d_in[0];
    float* out = (float*)d_out;
    int n_elem = in_sizes[0] / T_STEPS;       // 64*8192 = 524288
    int grid = n_elem / ELEMS;                // 8192 blocks, exact

    lif_kernel<<<grid, TPB, 0, stream>>>(x, out);
}